// Round 1
// baseline (147.592 us; speedup 1.0000x reference)
//
#include <hip/hip_runtime.h>
#include <math.h>

#define NB 8
#define CH 16
#define LL 1024
#define DD 7
#define SZH 112
#define HH 16

typedef float v2f __attribute__((ext_vector_type(2)));

#if __has_builtin(__builtin_amdgcn_exp2f)
#define EXP2F(x) __builtin_amdgcn_exp2f(x)
#else
#define EXP2F(x) exp2f(x)
#endif

// ---------------------------------------------------------------------------
// Kernel 1: QKV projection.
//   xf[n][l][c*7+dd] = x[n][c][l][dd]   (transpose-gather)
//   out[mat][n][h][l][j] = sum_i xf[n][l][i] * W[h*7+j][i] + b[h*7+j]
// stored padded to 8 floats per row (pad = 0) so kernel 2 can use float4.
// grid = 3 * NB * (LL/64) = 384 blocks, 256 threads.
// ---------------------------------------------------------------------------
__global__ __launch_bounds__(256, 2) void qkv_proj(
    const float* __restrict__ x,
    const float* __restrict__ Wq, const float* __restrict__ bq,
    const float* __restrict__ Wk, const float* __restrict__ bk,
    const float* __restrict__ Wv, const float* __restrict__ bv,
    float* __restrict__ qkv)
{
    // +1-style padding (113 = 112+1) -> conflict-free LDS access patterns
    __shared__ float Wt[112 * 113];   // Wt[i][j] = W[j][i]
    __shared__ float xt[64 * 113];    // xt[l][i] = xf[n][l0+l][i]

    int bx  = blockIdx.x;
    int mat = bx / (NB * 16);
    int rem = bx % (NB * 16);
    int n   = rem / 16;
    int l0  = (rem % 16) * 64;

    const float* W = (mat == 0) ? Wq : (mat == 1) ? Wk : Wv;
    const float* b = (mat == 0) ? bq : (mat == 1) ? bk : bv;

    int tid = threadIdx.x;

    // W (112x112 row-major [out][in]) -> transposed into LDS, coalesced reads
    for (int idx = tid; idx < 112 * 112; idx += 256) {
        int j = idx / 112;
        int i = idx - j * 112;
        Wt[i * 113 + j] = W[idx];
    }
    // x tile: contiguous runs of (l,dd) per channel c -> coalesced
    for (int idx = tid; idx < 64 * 112; idx += 256) {
        int c  = idx / 448;
        int r  = idx - c * 448;
        int l  = r / 7;
        int dd = r - l * 7;
        xt[l * 113 + c * 7 + dd] = x[((n * CH + c) * LL + l0 + l) * DD + dd];
    }
    __syncthreads();

    int jh = tid >> 4;   // head 0..15  (wave-slow index -> W reads broadcast)
    int lg = tid & 15;   // row group 0..15 (wave-fast index -> coalesced stores)

    float bias[7];
    #pragma unroll
    for (int j = 0; j < 7; ++j) bias[j] = b[jh * 7 + j];

    float acc[4][7];
    #pragma unroll
    for (int r = 0; r < 4; ++r)
        #pragma unroll
        for (int j = 0; j < 7; ++j) acc[r][j] = bias[j];

    // 11 LDS reads : 28 FMA per i
    for (int i = 0; i < 112; ++i) {
        float wv[7];
        #pragma unroll
        for (int j = 0; j < 7; ++j) wv[j] = Wt[i * 113 + jh * 7 + j];
        #pragma unroll
        for (int r = 0; r < 4; ++r) {
            float xv = xt[(r * 16 + lg) * 113 + i];
            #pragma unroll
            for (int j = 0; j < 7; ++j) acc[r][j] += xv * wv[j];
        }
    }

    // store: qkv[mat][n][jh][row][8], rows = l0 + r*16 + lg (lg fastest -> coalesced)
    #pragma unroll
    for (int r = 0; r < 4; ++r) {
        int row = l0 + r * 16 + lg;
        float4* dst = (float4*)(qkv + ((((size_t)mat * NB + n) * HH + jh) * LL + row) * 8);
        dst[0] = make_float4(acc[r][0], acc[r][1], acc[r][2], acc[r][3]);
        dst[1] = make_float4(acc[r][4], acc[r][5], acc[r][6], 0.0f);
    }
}

// ---------------------------------------------------------------------------
// Kernel 2: flash-style attention, no score materialization, no max-subtract
// (scores = q.k/32 bounded ~|8|, exp2 safe in fp32 -> partials add directly).
// grid = NB*HH*4 = 512 blocks (n, h, qtile of 256 rows), 256 threads.
// thread = (rowpair 0..127, keyhalf 0..1): 2 rows x 512 keys.
// ---------------------------------------------------------------------------
__global__ __launch_bounds__(256, 2) void attn(
    const float* __restrict__ qkv, float* __restrict__ out)
{
    __shared__ float4 K4[LL * 2];          // 32 KB
    __shared__ float4 V4[LL * 2];          // 32 KB
    __shared__ float4 red4[128 * 2 * 2];   // 8 KB partial (acc,l) from keyhalf 1

    int bx = blockIdx.x;
    int qt = bx & 3;
    int h  = (bx >> 2) & 15;
    int n  = bx >> 6;

    int tid = threadIdx.x;

    const float4* Qg4 = (const float4*)(qkv + (((size_t)(0 * NB + n) * HH + h) * LL) * 8);
    const float4* Kg4 = (const float4*)(qkv + (((size_t)(1 * NB + n) * HH + h) * LL) * 8);
    const float4* Vg4 = (const float4*)(qkv + (((size_t)(2 * NB + n) * HH + h) * LL) * 8);

    for (int idx = tid; idx < LL * 2; idx += 256) {
        K4[idx] = Kg4[idx];
        V4[idx] = Vg4[idx];
    }

    int rp   = tid & 127;     // row pair
    int kh   = tid >> 7;      // key half
    int row0 = qt * 256 + rp * 2;

    const float SCALE = 1.44269504088896340736f / 32.0f;  // log2(e)/sqrt(L)

    v2f q[2][4];
    #pragma unroll
    for (int rr = 0; rr < 2; ++rr) {
        float4 a  = Qg4[(row0 + rr) * 2];
        float4 bb = Qg4[(row0 + rr) * 2 + 1];
        q[rr][0] = (v2f){a.x * SCALE, a.y * SCALE};
        q[rr][1] = (v2f){a.z * SCALE, a.w * SCALE};
        q[rr][2] = (v2f){bb.x * SCALE, bb.y * SCALE};
        q[rr][3] = (v2f){bb.z * SCALE, bb.w * SCALE};
    }

    v2f   acc[2][4] = {};
    float lsum[2]   = {0.f, 0.f};

    __syncthreads();

    // all 64 lanes of a wave read the SAME K/V address -> LDS broadcast, 0 conflicts
    int k0 = kh * 512;
    for (int kk = k0; kk < k0 + 512; ++kk) {
        float4 ka = K4[kk * 2], kb = K4[kk * 2 + 1];
        float4 va = V4[kk * 2], vb = V4[kk * 2 + 1];
        v2f kv0 = (v2f){ka.x, ka.y}, kv1 = (v2f){ka.z, ka.w};
        v2f kv2 = (v2f){kb.x, kb.y}, kv3 = (v2f){kb.z, kb.w};
        v2f vv0 = (v2f){va.x, va.y}, vv1 = (v2f){va.z, va.w};
        v2f vv2 = (v2f){vb.x, vb.y}, vv3 = (v2f){vb.z, vb.w};
        #pragma unroll
        for (int rr = 0; rr < 2; ++rr) {
            v2f d = q[rr][0] * kv0;
            d += q[rr][1] * kv1;
            d += q[rr][2] * kv2;
            d += q[rr][3] * kv3;
            float s = d.x + d.y;            // pads are 0 on both sides
            float p = EXP2F(s);
            lsum[rr] += p;
            v2f p2 = (v2f){p, p};
            acc[rr][0] += p2 * vv0;
            acc[rr][1] += p2 * vv1;
            acc[rr][2] += p2 * vv2;
            acc[rr][3] += p2 * vv3;
        }
    }

    // combine the two key-halves through LDS (plain adds: no max rescaling)
    if (kh == 1) {
        #pragma unroll
        for (int rr = 0; rr < 2; ++rr) {
            red4[(rp * 2 + rr) * 2]     = make_float4(acc[rr][0].x, acc[rr][0].y,
                                                      acc[rr][1].x, acc[rr][1].y);
            red4[(rp * 2 + rr) * 2 + 1] = make_float4(acc[rr][2].x, acc[rr][2].y,
                                                      acc[rr][3].x, lsum[rr]);
        }
    }
    __syncthreads();
    if (kh == 0) {
        #pragma unroll
        for (int rr = 0; rr < 2; ++rr) {
            float4 a  = red4[(rp * 2 + rr) * 2];
            float4 bb = red4[(rp * 2 + rr) * 2 + 1];
            float l = lsum[rr] + bb.w;
            float o[7];
            o[0] = acc[rr][0].x + a.x;  o[1] = acc[rr][0].y + a.y;
            o[2] = acc[rr][1].x + a.z;  o[3] = acc[rr][1].y + a.w;
            o[4] = acc[rr][2].x + bb.x; o[5] = acc[rr][2].y + bb.y;
            o[6] = acc[rr][3].x + bb.z;
            float inv = 1.0f / l;
            float* dst = out + (((size_t)n * HH + h) * LL + row0 + rr) * 7;
            #pragma unroll
            for (int j = 0; j < 7; ++j) dst[j] = o[j] * inv;
        }
    }
}

extern "C" void kernel_launch(void* const* d_in, const int* in_sizes, int n_in,
                              void* d_out, int out_size, void* d_ws, size_t ws_size,
                              hipStream_t stream) {
    const float* x  = (const float*)d_in[0];
    const float* Wq = (const float*)d_in[1];
    const float* bq = (const float*)d_in[2];
    const float* Wk = (const float*)d_in[3];
    const float* bk = (const float*)d_in[4];
    const float* Wv = (const float*)d_in[5];
    const float* bv = (const float*)d_in[6];
    float* qkv = (float*)d_ws;   // [3][NB][HH][LL][8] fp32 = 12.6 MB
    float* o   = (float*)d_out;

    qkv_proj<<<dim3(3 * NB * 16), dim3(256), 0, stream>>>(x, Wq, bq, Wk, bk, Wv, bv, qkv);
    attn<<<dim3(NB * HH * 4), dim3(256), 0, stream>>>(qkv, o);
}

// Round 2
// 115.722 us; speedup vs baseline: 1.2754x; 1.2754x over previous
//
#include <hip/hip_runtime.h>
#include <math.h>

#define NB 8
#define CH 16
#define LL 1024
#define DD 7
#define HH 16

typedef float  v4f __attribute__((ext_vector_type(4)));
typedef short  v8s __attribute__((ext_vector_type(8)));

#if __has_builtin(__builtin_amdgcn_exp2f)
#define EXP2F(x) __builtin_amdgcn_exp2f(x)
#else
#define EXP2F(x) exp2f(x)
#endif

__device__ inline unsigned bf16_rne(float f) {
    unsigned u = __builtin_bit_cast(unsigned, f);
    return (u + 0x7fffu + ((u >> 16) & 1u)) >> 16;   // round-to-nearest-even
}
// pack two fp32 -> two bf16 (truncation; bias cancels in softmax ratio)
__device__ inline unsigned pack_trunc(float a, float b) {
    unsigned ua = __builtin_bit_cast(unsigned, a);
    unsigned ub = __builtin_bit_cast(unsigned, b);
    return (ua >> 16) | (ub & 0xffff0000u);
}

// ---------------------------------------------------------------------------
// Kernel 1: QKV projection (fp32 math, bf16 output padded [mat][n][h][1024][8]).
// W kept untransposed in LDS -> all main-loop LDS reads are ds_read_b128.
// Q is pre-scaled by log2(e)/sqrt(L) so attn's exp2 needs no multiply.
// grid = 3*NB*16 = 384 blocks, 256 threads.
// ---------------------------------------------------------------------------
__global__ __launch_bounds__(256, 2) void qkv_proj(
    const float* __restrict__ x,
    const float* __restrict__ Wq, const float* __restrict__ bq,
    const float* __restrict__ Wk, const float* __restrict__ bk,
    const float* __restrict__ Wv, const float* __restrict__ bv,
    unsigned short* __restrict__ qkvb)
{
    __shared__ __align__(16) float Ws[112 * 112];   // W[j][i], i contiguous (50.2 KB)
    __shared__ __align__(16) float xt[64 * 116];    // xf rows, stride 116 (29.7 KB)

    int bx  = blockIdx.x;
    int mat = bx / (NB * 16);
    int rem = bx % (NB * 16);
    int n   = rem / 16;
    int l0  = (rem % 16) * 64;

    const float* W = (mat == 0) ? Wq : (mat == 1) ? Wk : Wv;
    const float* b = (mat == 0) ? bq : (mat == 1) ? bk : bv;

    int tid = threadIdx.x;

    for (int idx = tid; idx < 112 * 112; idx += 256) Ws[idx] = W[idx];  // straight copy
    for (int idx = tid; idx < 64 * 112; idx += 256) {
        int c  = idx / 448;
        int r  = idx - c * 448;
        int l  = r / 7;
        int dd = r - l * 7;
        xt[l * 116 + c * 7 + dd] = x[((n * CH + c) * LL + l0 + l) * DD + dd];
    }
    __syncthreads();

    int jh = tid >> 4;   // head (wave-slow -> W reads broadcast)
    int lg = tid & 15;   // row group (wave-fast -> coalesced stores)

    float acc[4][7];
    #pragma unroll
    for (int j = 0; j < 7; ++j) {
        float bj = b[jh * 7 + j];
        #pragma unroll
        for (int r = 0; r < 4; ++r) acc[r][j] = bj;
    }

    // 11 ds_read_b128 per 112 FMA
    for (int i4 = 0; i4 < 28; ++i4) {
        float4 wv[7];
        #pragma unroll
        for (int j = 0; j < 7; ++j)
            wv[j] = *(const float4*)&Ws[(jh * 7 + j) * 112 + i4 * 4];
        #pragma unroll
        for (int r = 0; r < 4; ++r) {
            float4 xv = *(const float4*)&xt[(r * 16 + lg) * 116 + i4 * 4];
            #pragma unroll
            for (int j = 0; j < 7; ++j) {
                acc[r][j] += xv.x * wv[j].x;
                acc[r][j] += xv.y * wv[j].y;
                acc[r][j] += xv.z * wv[j].z;
                acc[r][j] += xv.w * wv[j].w;
            }
        }
    }

    const float scale = (mat == 0) ? 0.0450842200277801f /* log2(e)/32 */ : 1.0f;
    #pragma unroll
    for (int r = 0; r < 4; ++r) {
        int row = l0 + r * 16 + lg;
        unsigned d0 = bf16_rne(acc[r][0] * scale) | (bf16_rne(acc[r][1] * scale) << 16);
        unsigned d1 = bf16_rne(acc[r][2] * scale) | (bf16_rne(acc[r][3] * scale) << 16);
        unsigned d2 = bf16_rne(acc[r][4] * scale) | (bf16_rne(acc[r][5] * scale) << 16);
        unsigned d3 = bf16_rne(acc[r][6] * scale);                    // pad col 7 = 0
        uint4* dst = (uint4*)qkvb + (((size_t)(mat * NB + n) * HH + jh) * LL + row);
        *dst = make_uint4(d0, d1, d2, d3);
    }
}

// ---------------------------------------------------------------------------
// Kernel 2: MFMA flash attention.
//  S^T tiles = mfma(A=K, B=Q)  -> C layout gives 4 consecutive KEYS per lane
//  -> exp2 -> pack bf16 -> one ds_write_b64 per tile -> P rows in LDS
//  PV = mfma(A=P, B=V^T) with V column 7 == 1.0 => rowsum free in output col 7.
// grid = NB*HH*4 = 512 blocks (n,h,qtile of 256 rows), 256 thr; wave = 64 rows.
// ---------------------------------------------------------------------------
__global__ __launch_bounds__(256, 2) void attn(
    const unsigned short* __restrict__ qkvb, float* __restrict__ out)
{
    // carve: Kl [1024][8] (16384 B) | Vt [8][1032] (16512 B) | Pb 20480 B
    __shared__ __align__(16) unsigned short sm[(16384 + 16512 + 20480) / 2];
    unsigned short* Kl = sm;
    unsigned short* Vt = sm + 8192;
    unsigned short* Pb = sm + 8192 + 8256;   // also used as Vtmp during staging

    int bx = blockIdx.x;
    int qt = bx & 3, h = (bx >> 2) & 15, n = bx >> 6;
    int tid  = threadIdx.x;
    int wave = tid >> 6, lane = tid & 63, l15 = lane & 15, l4 = lane >> 4;

    const unsigned short* Qg = qkvb + (size_t)((0 * NB + n) * HH + h) * (LL * 8);
    const unsigned short* Kg = qkvb + (size_t)((1 * NB + n) * HH + h) * (LL * 8);
    const unsigned short* Vg = qkvb + (size_t)((2 * NB + n) * HH + h) * (LL * 8);

    // phase 0: K -> Kl, V -> Vtmp (coalesced 16B)
    {
        const uint4* Ks = (const uint4*)Kg;
        const uint4* Vs = (const uint4*)Vg;
        uint4* Kd = (uint4*)Kl;
        uint4* Vd = (uint4*)Pb;
        for (int i = tid; i < LL; i += 256) { Kd[i] = Ks[i]; Vd[i] = Vs[i]; }
    }
    __syncthreads();

    // phase 1: transpose Vtmp[1024][8] -> Vt[8][1032], dim 7 := 1.0 (ones column)
    {
        const uint4* Vd = (const uint4*)Pb;
        uint4 r0 = Vd[4 * tid + 0], r1 = Vd[4 * tid + 1];
        uint4 r2 = Vd[4 * tid + 2], r3 = Vd[4 * tid + 3];
        const unsigned* p0 = (const unsigned*)&r0;
        const unsigned* p1 = (const unsigned*)&r1;
        const unsigned* p2 = (const unsigned*)&r2;
        const unsigned* p3 = (const unsigned*)&r3;
        #pragma unroll
        for (int d = 0; d < 7; ++d) {
            unsigned a0 = p0[d >> 1], a1 = p1[d >> 1], a2 = p2[d >> 1], a3 = p3[d >> 1];
            unsigned w0, w1;
            if (d & 1) { w0 = (a0 >> 16) | (a1 & 0xffff0000u); w1 = (a2 >> 16) | (a3 & 0xffff0000u); }
            else       { w0 = (a0 & 0xffffu) | (a1 << 16);     w1 = (a2 & 0xffffu) | (a3 << 16); }
            *(uint2*)&Vt[d * 1032 + 4 * tid] = make_uint2(w0, w1);
        }
        *(uint2*)&Vt[7 * 1032 + 4 * tid] = make_uint2(0x3f803f80u, 0x3f803f80u);
    }
    __syncthreads();

    int qbase = qt * 256 + wave * 64;
    v8s zero8 = {0, 0, 0, 0, 0, 0, 0, 0};

    // Q B-frags straight from global: lane<16 holds Q[qrow][0..7] (k=0..7; rest 0)
    v8s qf[4];
    #pragma unroll
    for (int t = 0; t < 4; ++t)
        qf[t] = (lane < 16) ? *(const v8s*)(Qg + (size_t)(qbase + t * 16 + l15) * 8) : zero8;

    v4f acc[4];
    #pragma unroll
    for (int t = 0; t < 4; ++t) acc[t] = (v4f){0.f, 0.f, 0.f, 0.f};

    unsigned short* Pw = Pb + wave * 2560;   // private [64 q][40 (32 keys + pad)]

    for (int c = 0; c < 32; ++c) {           // 32-key chunks
        #pragma unroll
        for (int s = 0; s < 2; ++s) {
            v8s kf = (lane < 16) ? *(const v8s*)(Kl + (c * 32 + s * 16 + l15) * 8) : zero8;
            #pragma unroll
            for (int t = 0; t < 4; ++t) {
                // S^T tile: rows = keys (4 consecutive per lane), cols = q-rows
                v4f sc = __builtin_amdgcn_mfma_f32_16x16x32_bf16(
                             kf, qf[t], (v4f){0.f, 0.f, 0.f, 0.f}, 0, 0, 0);
                float e0 = EXP2F(sc[0]), e1 = EXP2F(sc[1]);
                float e2 = EXP2F(sc[2]), e3 = EXP2F(sc[3]);
                unsigned w0 = pack_trunc(e0, e1), w1 = pack_trunc(e2, e3);
                *(uint2*)&Pw[(t * 16 + l15) * 40 + s * 16 + l4 * 4] = make_uint2(w0, w1);
            }
        }
        // V^T B-frag: lane(n=l15<8) reads Vt[n][8 consecutive keys]; ones col at n=7
        v8s vf = (l15 < 8) ? *(const v8s*)(Vt + l15 * 1032 + c * 32 + l4 * 8) : zero8;
        #pragma unroll
        for (int t = 0; t < 4; ++t) {
            v8s pf = *(const v8s*)&Pw[(t * 16 + l15) * 40 + l4 * 8];
            acc[t] = __builtin_amdgcn_mfma_f32_16x16x32_bf16(pf, vf, acc[t], 0, 0, 0);
        }
    }

    // epilogue: col 7 of acc = rowsum; divide and store dims 0..6
    size_t obase = (size_t)(n * HH + h) * LL * 7;
    #pragma unroll
    for (int t = 0; t < 4; ++t) {
        #pragma unroll
        for (int r = 0; r < 4; ++r) {
            float val = acc[t][r];
            float rs  = __shfl(val, 7, 16);    // broadcast col-7 within 16-lane seg
            if (l15 < 7)
                out[obase + (size_t)(qbase + t * 16 + l4 * 4 + r) * 7 + l15] = val / rs;
        }
    }
}

extern "C" void kernel_launch(void* const* d_in, const int* in_sizes, int n_in,
                              void* d_out, int out_size, void* d_ws, size_t ws_size,
                              hipStream_t stream) {
    const float* x  = (const float*)d_in[0];
    const float* Wq = (const float*)d_in[1];
    const float* bq = (const float*)d_in[2];
    const float* Wk = (const float*)d_in[3];
    const float* bk = (const float*)d_in[4];
    const float* Wv = (const float*)d_in[5];
    const float* bv = (const float*)d_in[6];
    unsigned short* qkvb = (unsigned short*)d_ws;  // [3][8][16][1024][8] bf16 = 6 MB
    float* o = (float*)d_out;

    qkv_proj<<<dim3(3 * NB * 16), dim3(256), 0, stream>>>(x, Wq, bq, Wk, bk, Wv, bv, qkvb);
    attn<<<dim3(NB * HH * 4), dim3(256), 0, stream>>>(qkvb, o);
}

// Round 3
// 110.375 us; speedup vs baseline: 1.3372x; 1.0484x over previous
//
#include <hip/hip_runtime.h>
#include <math.h>

#define NB 8
#define CH 16
#define LL 1024
#define DD 7
#define HH 16

typedef float  v2f  __attribute__((ext_vector_type(2)));
typedef float  v4f  __attribute__((ext_vector_type(4)));
typedef float  v16f __attribute__((ext_vector_type(16)));
typedef short  v8s  __attribute__((ext_vector_type(8)));

#if __has_builtin(__builtin_amdgcn_exp2f)
#define EXP2F(x) __builtin_amdgcn_exp2f(x)
#else
#define EXP2F(x) exp2f(x)
#endif

__device__ inline unsigned bf16_rne(float f) {
    unsigned u = __builtin_bit_cast(unsigned, f);
    return (u + 0x7fffu + ((u >> 16) & 1u)) >> 16;
}
__device__ inline unsigned pack_trunc(float a, float b) {
    unsigned ua = __builtin_bit_cast(unsigned, a);
    unsigned ub = __builtin_bit_cast(unsigned, b);
    return (ua >> 16) | (ub & 0xffff0000u);
}

// ---------------------------------------------------------------------------
// Kernel 1: QKV projection (fp32 math via v_pk_fma_f32 pairs, bf16 output
// padded [mat][n][h][1024][8]). Q pre-scaled by log2(e)/32.
// grid = 3*NB*16 = 384 blocks, 256 threads.
// ---------------------------------------------------------------------------
__global__ __launch_bounds__(256, 2) void qkv_proj(
    const float* __restrict__ x,
    const float* __restrict__ Wq, const float* __restrict__ bq,
    const float* __restrict__ Wk, const float* __restrict__ bk,
    const float* __restrict__ Wv, const float* __restrict__ bv,
    unsigned short* __restrict__ qkvb)
{
    __shared__ __align__(16) float Ws[112 * 112];   // W[j][i], i contiguous
    __shared__ __align__(16) float xt[64 * 116];    // xf rows, stride 116

    int bx  = blockIdx.x;
    int mat = bx / (NB * 16);
    int rem = bx % (NB * 16);
    int n   = rem / 16;
    int l0  = (rem % 16) * 64;

    const float* W = (mat == 0) ? Wq : (mat == 1) ? Wk : Wv;
    const float* b = (mat == 0) ? bq : (mat == 1) ? bk : bv;

    int tid = threadIdx.x;

    {   // W staging: 3136 uint4, coalesced
        const uint4* src = (const uint4*)W;
        uint4* dst = (uint4*)Ws;
        for (int i = tid; i < 3136; i += 256) dst[i] = src[i];
    }
    for (int idx = tid; idx < 64 * 112; idx += 256) {
        int c  = idx / 448;
        int r  = idx - c * 448;
        int l  = r / 7;
        int dd = r - l * 7;
        xt[l * 116 + c * 7 + dd] = x[((n * CH + c) * LL + l0 + l) * DD + dd];
    }
    __syncthreads();

    int jh = tid >> 4;   // head (wave-slow -> W reads broadcast)
    int lg = tid & 15;   // row group (wave-fast -> coalesced stores)

    v2f acc2[2][7];
    #pragma unroll
    for (int j = 0; j < 7; ++j) {
        float bj = b[jh * 7 + j];
        acc2[0][j] = (v2f){bj, bj};
        acc2[1][j] = (v2f){bj, bj};
    }

    const v4f* Wv4 = (const v4f*)Ws;
    const v4f* Xv4 = (const v4f*)xt;

    for (int i4 = 0; i4 < 28; ++i4) {
        v4f wv[7];
        #pragma unroll
        for (int j = 0; j < 7; ++j) wv[j] = Wv4[(jh * 7 + j) * 28 + i4];
        v4f x0 = Xv4[(0  + lg) * 29 + i4];
        v4f x1 = Xv4[(16 + lg) * 29 + i4];
        v4f x2 = Xv4[(32 + lg) * 29 + i4];
        v4f x3 = Xv4[(48 + lg) * 29 + i4];
        #pragma unroll
        for (int f = 0; f < 4; ++f) {
            v2f xa = (v2f){x0[f], x1[f]};
            v2f xb = (v2f){x2[f], x3[f]};
            #pragma unroll
            for (int j = 0; j < 7; ++j) {
                v2f wj = (v2f){wv[j][f], wv[j][f]};
                acc2[0][j] += xa * wj;      // v_pk_fma_f32
                acc2[1][j] += xb * wj;
            }
        }
    }

    const float scale = (mat == 0) ? 0.0450842200277801f /* log2(e)/32 */ : 1.0f;
    #pragma unroll
    for (int rp = 0; rp < 2; ++rp) {
        #pragma unroll
        for (int e = 0; e < 2; ++e) {
            int r = rp * 2 + e;
            float a0 = acc2[rp][0][e] * scale, a1 = acc2[rp][1][e] * scale;
            float a2 = acc2[rp][2][e] * scale, a3 = acc2[rp][3][e] * scale;
            float a4 = acc2[rp][4][e] * scale, a5 = acc2[rp][5][e] * scale;
            float a6 = acc2[rp][6][e] * scale;
            unsigned d0 = bf16_rne(a0) | (bf16_rne(a1) << 16);
            unsigned d1 = bf16_rne(a2) | (bf16_rne(a3) << 16);
            unsigned d2 = bf16_rne(a4) | (bf16_rne(a5) << 16);
            unsigned d3 = bf16_rne(a6);                     // pad col 7 = 0
            int row = l0 + r * 16 + lg;
            uint4* dst = (uint4*)qkvb + ((size_t)(mat * NB + n) * HH + jh) * LL + row;
            *dst = make_uint4(d0, d1, d2, d3);
        }
    }
}

// ---------------------------------------------------------------------------
// Kernel 2: MFMA flash attention.
//  S^T = mfma_32x32x16(A=K, B=Q): C-layout key = (reg&3)+8*(reg>>2)+4*(lane>>5)
//  key->slot perm: slot = 16*(lane>>5) + reg  => lane's 16 exp'd values are
//  CONTIGUOUS -> 2x ds_write_b128 in natural reg order. Vt columns stored with
//  the same slot perm so PV = mfma_16x16x32(A=P, B=V^T) contracts consistently.
//  V col 7 == 1.0 => softmax denominator free in output col 7.
// grid = NB*HH*4 = 512 blocks (n,h,qtile 256), 256 thr; wave = 64 q rows.
// ---------------------------------------------------------------------------
__global__ __launch_bounds__(256, 2) void attn(
    const unsigned short* __restrict__ qkvb, float* __restrict__ out)
{
    __shared__ __align__(16) unsigned short Kl[LL * 8];        // 16 KB
    __shared__ __align__(16) unsigned short Vt[8 * 1040];      // 16.25 KB (slot-permuted)
    __shared__ __align__(16) unsigned short Pb[4 * 64 * 40];   // 20 KB (per-wave P)

    int bx = blockIdx.x;
    int qt = bx & 3, h = (bx >> 2) & 15, n = bx >> 6;
    int tid  = threadIdx.x;
    int wave = tid >> 6, lane = tid & 63;
    int l31 = lane & 31, g5 = lane >> 5, l15 = lane & 15, l4 = lane >> 4;

    const unsigned short* Qg = qkvb + (size_t)((0 * NB + n) * HH + h) * (LL * 8);
    const unsigned short* Kg = qkvb + (size_t)((1 * NB + n) * HH + h) * (LL * 8);
    const unsigned short* Vg = qkvb + (size_t)((2 * NB + n) * HH + h) * (LL * 8);

    {   // stage K -> Kl, V -> Pb (temp), coalesced 16B
        const uint4* Ks = (const uint4*)Kg;
        const uint4* Vs = (const uint4*)Vg;
        uint4* Kd = (uint4*)Kl;
        uint4* Vd = (uint4*)Pb;
        #pragma unroll
        for (int it = 0; it < 4; ++it) {
            int i = tid + it * 256;
            Kd[i] = Ks[i];
            Vd[i] = Vs[i];
        }
    }
    __syncthreads();

    {   // transpose + slot-permute V -> Vt[8][1040]; thread owns keys 4t..4t+3
        const uint4* Vd = (const uint4*)Pb;
        uint4 r0 = Vd[4 * tid], r1 = Vd[4 * tid + 1];
        uint4 r2 = Vd[4 * tid + 2], r3 = Vd[4 * tid + 3];
        const unsigned* p0 = (const unsigned*)&r0;
        const unsigned* p1 = (const unsigned*)&r1;
        const unsigned* p2 = (const unsigned*)&r2;
        const unsigned* p3 = (const unsigned*)&r3;
        int col = ((tid >> 3) << 5) + ((tid & 1) << 4) + (((tid >> 1) & 3) << 2);
        #pragma unroll
        for (int d = 0; d < 7; ++d) {
            unsigned a0 = p0[d >> 1], a1 = p1[d >> 1], a2 = p2[d >> 1], a3 = p3[d >> 1];
            unsigned w0, w1;
            if (d & 1) { w0 = (a0 >> 16) | (a1 & 0xffff0000u); w1 = (a2 >> 16) | (a3 & 0xffff0000u); }
            else       { w0 = (a0 & 0xffffu) | (a1 << 16);     w1 = (a2 & 0xffffu) | (a3 << 16); }
            *(uint2*)&Vt[d * 1040 + col] = make_uint2(w0, w1);
        }
        *(uint2*)&Vt[7 * 1040 + col] = make_uint2(0x3f803f80u, 0x3f803f80u);
    }
    __syncthreads();

    int qbase = qt * 256 + wave * 64;
    v8s zero8 = {0, 0, 0, 0, 0, 0, 0, 0};
    v8s qf0 = (lane < 32) ? *(const v8s*)(Qg + (size_t)(qbase + l31) * 8)      : zero8;
    v8s qf1 = (lane < 32) ? *(const v8s*)(Qg + (size_t)(qbase + 32 + l31) * 8) : zero8;

    v4f acc[4];
    #pragma unroll
    for (int st = 0; st < 4; ++st) acc[st] = (v4f){0.f, 0.f, 0.f, 0.f};

    unsigned short* Pw = Pb + wave * (64 * 40);

    #pragma unroll 2
    for (int c = 0; c < 32; ++c) {
        v8s kf = (lane < 32) ? *(const v8s*)(Kl + (c * 32 + l31) * 8) : zero8;
        v16f s0 = __builtin_amdgcn_mfma_f32_32x32x16_bf16(kf, qf0, (v16f){}, 0, 0, 0);
        v16f s1 = __builtin_amdgcn_mfma_f32_32x32x16_bf16(kf, qf1, (v16f){}, 0, 0, 0);
        {
            unsigned short* dst = Pw + l31 * 40 + (g5 << 4);
            uint4 wa, wb;
            wa.x = pack_trunc(EXP2F(s0[0]),  EXP2F(s0[1]));
            wa.y = pack_trunc(EXP2F(s0[2]),  EXP2F(s0[3]));
            wa.z = pack_trunc(EXP2F(s0[4]),  EXP2F(s0[5]));
            wa.w = pack_trunc(EXP2F(s0[6]),  EXP2F(s0[7]));
            wb.x = pack_trunc(EXP2F(s0[8]),  EXP2F(s0[9]));
            wb.y = pack_trunc(EXP2F(s0[10]), EXP2F(s0[11]));
            wb.z = pack_trunc(EXP2F(s0[12]), EXP2F(s0[13]));
            wb.w = pack_trunc(EXP2F(s0[14]), EXP2F(s0[15]));
            *(uint4*)dst       = wa;
            *(uint4*)(dst + 8) = wb;
        }
        {
            unsigned short* dst = Pw + (32 + l31) * 40 + (g5 << 4);
            uint4 wa, wb;
            wa.x = pack_trunc(EXP2F(s1[0]),  EXP2F(s1[1]));
            wa.y = pack_trunc(EXP2F(s1[2]),  EXP2F(s1[3]));
            wa.z = pack_trunc(EXP2F(s1[4]),  EXP2F(s1[5]));
            wa.w = pack_trunc(EXP2F(s1[6]),  EXP2F(s1[7]));
            wb.x = pack_trunc(EXP2F(s1[8]),  EXP2F(s1[9]));
            wb.y = pack_trunc(EXP2F(s1[10]), EXP2F(s1[11]));
            wb.z = pack_trunc(EXP2F(s1[12]), EXP2F(s1[13]));
            wb.w = pack_trunc(EXP2F(s1[14]), EXP2F(s1[15]));
            *(uint4*)dst       = wa;
            *(uint4*)(dst + 8) = wb;
        }
        v8s vf = (l15 < 8) ? *(const v8s*)(Vt + l15 * 1040 + c * 32 + l4 * 8) : zero8;
        #pragma unroll
        for (int st = 0; st < 4; ++st) {
            v8s pf = *(const v8s*)(Pw + (st * 16 + l15) * 40 + l4 * 8);
            acc[st] = __builtin_amdgcn_mfma_f32_16x16x32_bf16(pf, vf, acc[st], 0, 0, 0);
        }
    }

    // epilogue: col 7 of acc = rowsum; divide and store dims 0..6
    size_t obase = (size_t)(n * HH + h) * LL * 7;
    #pragma unroll
    for (int st = 0; st < 4; ++st) {
        #pragma unroll
        for (int r = 0; r < 4; ++r) {
            float val = acc[st][r];
            float rs  = __shfl(val, 7, 16);   // broadcast col-7 within 16-lane seg
            if (l15 < 7)
                out[obase + (size_t)(qbase + st * 16 + l4 * 4 + r) * 7 + l15] = val / rs;
        }
    }
}

extern "C" void kernel_launch(void* const* d_in, const int* in_sizes, int n_in,
                              void* d_out, int out_size, void* d_ws, size_t ws_size,
                              hipStream_t stream) {
    const float* x  = (const float*)d_in[0];
    const float* Wq = (const float*)d_in[1];
    const float* bq = (const float*)d_in[2];
    const float* Wk = (const float*)d_in[3];
    const float* bk = (const float*)d_in[4];
    const float* Wv = (const float*)d_in[5];
    const float* bv = (const float*)d_in[6];
    unsigned short* qkvb = (unsigned short*)d_ws;  // [3][8][16][1024][8] bf16 = 6 MB
    float* o = (float*)d_out;

    qkv_proj<<<dim3(3 * NB * 16), dim3(256), 0, stream>>>(x, Wq, bq, Wk, bk, Wv, bv, qkvb);
    attn<<<dim3(NB * HH * 4), dim3(256), 0, stream>>>(qkvb, o);
}